// Round 2
// 6193.165 us; speedup vs baseline: 1.7089x; 1.7089x over previous
//
#include <hip/hip_runtime.h>
#include <math.h>

// Problem constants (BertCrf)
#define NB   16      // batch
#define SS   128     // seq len
#define HH   768     // hidden
#define NHD  12      // heads
#define DHD  64      // head dim
#define FFD  3072    // ffn dim
#define NLAY 12      // layers
#define NT   9       // tags
#define TOK  (NB*SS) // 2048 tokens

typedef __attribute__((ext_vector_type(4))) float    f32x4;
typedef __attribute__((ext_vector_type(4))) _Float16 f16x4;
typedef __attribute__((ext_vector_type(8))) _Float16 f16x8;

__device__ __forceinline__ float wave_sum(float v) {
#pragma unroll
    for (int o = 32; o > 0; o >>= 1) v += __shfl_down(v, o, 64);
    return v;
}

// Markidis split: x = h + l * 2^-12, h/l fp16. (x - (float)h) exact (Sterbenz).
// Per-product error ~3*2^-22 relative -> below fp32 reorder noise.
// Whole-vector form: clang forbids non-const refs to vector elements.
__device__ __forceinline__ void split4(float4 v, f16x4& hv, f16x4& lv) {
    _Float16 h0 = (_Float16)v.x;
    _Float16 h1 = (_Float16)v.y;
    _Float16 h2 = (_Float16)v.z;
    _Float16 h3 = (_Float16)v.w;
    _Float16 l0 = (_Float16)((v.x - (float)h0) * 4096.0f);
    _Float16 l1 = (_Float16)((v.y - (float)h1) * 4096.0f);
    _Float16 l2 = (_Float16)((v.z - (float)h2) * 4096.0f);
    _Float16 l3 = (_Float16)((v.w - (float)h3) * 4096.0f);
    hv = (f16x4){h0, h1, h2, h3};
    lv = (f16x4){l0, l1, l2, l3};
}

// LDS layout: row-major [row][32 k] fp16 (64 B/row), XOR swizzle on the 16B
// slot so fragment ds_read_b128 across 16 rows is 2-way (free) not 16-way.
__device__ __forceinline__ int lds_off(int row, int kbyte) {
    return (row << 6) + (kbyte ^ (((row >> 1) & 3) << 4));
}

// ---------------- split-f16 MFMA GEMM core ----------------
// C[M x N] = A[M x K] @ W[K x N] + bias, fp32 in/out, fp32-grade accuracy.
// Tile 64(M) x 128(N), BK=32, 256 threads = 4 waves (2x2), wave = 32x64 out.
__device__ __forceinline__ void gemm_core(
    const float* __restrict__ A, const float* __restrict__ W,
    const float* __restrict__ bias, float* __restrict__ C,
    int N, int K, int row0, int col0)
{
    __shared__ __align__(16) char lds[24576];
    char* aH = lds;             // 64 rows * 64B
    char* aL = lds + 4096;
    char* bH = lds + 8192;      // 128 rows * 64B
    char* bL = lds + 16384;

    const int tid  = threadIdx.x;
    const int lane = tid & 63;
    const int wid  = tid >> 6;
    const int wr   = wid >> 1;          // wave row 0..1
    const int wc   = wid & 1;           // wave col 0..1
    const int lrow = lane & 15;
    const int kby  = (lane >> 4) << 4;  // frag k byte offset: (lane>>4)*8 elems * 2B

    // A staging: 64 rows x 32 k fp32, 8 threads/row, 2 rows per thread
    const int ar0 = tid >> 3;           // 0..31
    const int ar1 = ar0 + 32;           // 32..63
    const int ak  = (tid & 7) << 2;     // k 0,4,...,28
    const int ak2 = ak << 1;            // byte offset
    // B staging: 4k x 4n micro-transpose per thread
    const int bkb = tid >> 5;           // k group 0..7
    const int bn  = (tid & 31) << 2;    // n 0..124
    const int kb2 = bkb << 3;           // byte offset of k group

    const float* Ap0 = A + (size_t)(row0 + ar0) * K + ak;
    const float* Ap1 = A + (size_t)(row0 + ar1) * K + ak;
    const float* Wp  = W + (size_t)(bkb << 2) * N + col0 + bn;

    f32x4 acc1[2][4] = {};
    f32x4 acc2[2][4] = {};

    // prefetch tile 0
    float4 av0 = *(const float4*)Ap0;
    float4 av1 = *(const float4*)Ap1;
    float4 w0  = *(const float4*)(Wp);
    float4 w1  = *(const float4*)(Wp + N);
    float4 w2  = *(const float4*)(Wp + 2 * (size_t)N);
    float4 w3  = *(const float4*)(Wp + 3 * (size_t)N);

    for (int k0 = 0; k0 < K; k0 += 32) {
        __syncthreads();   // previous iter's LDS reads complete
        // ---- convert + stage A
        {
            f16x4 hv, lv;
            split4(av0, hv, lv);
            *(f16x4*)(aH + lds_off(ar0, ak2)) = hv;
            *(f16x4*)(aL + lds_off(ar0, ak2)) = lv;
            split4(av1, hv, lv);
            *(f16x4*)(aH + lds_off(ar1, ak2)) = hv;
            *(f16x4*)(aL + lds_off(ar1, ak2)) = lv;
        }
        // ---- convert + stage B (4x4 in-register transpose: [k][n] -> [n][k])
        {
            f16x4 hv, lv;
            split4(make_float4(w0.x, w1.x, w2.x, w3.x), hv, lv);
            *(f16x4*)(bH + lds_off(bn + 0, kb2)) = hv;
            *(f16x4*)(bL + lds_off(bn + 0, kb2)) = lv;
            split4(make_float4(w0.y, w1.y, w2.y, w3.y), hv, lv);
            *(f16x4*)(bH + lds_off(bn + 1, kb2)) = hv;
            *(f16x4*)(bL + lds_off(bn + 1, kb2)) = lv;
            split4(make_float4(w0.z, w1.z, w2.z, w3.z), hv, lv);
            *(f16x4*)(bH + lds_off(bn + 2, kb2)) = hv;
            *(f16x4*)(bL + lds_off(bn + 2, kb2)) = lv;
            split4(make_float4(w0.w, w1.w, w2.w, w3.w), hv, lv);
            *(f16x4*)(bH + lds_off(bn + 3, kb2)) = hv;
            *(f16x4*)(bL + lds_off(bn + 3, kb2)) = lv;
        }
        __syncthreads();
        // ---- prefetch next K tile (hides HBM/L2 latency under MFMA phase)
        if (k0 + 32 < K) {
            av0 = *(const float4*)(Ap0 + k0 + 32);
            av1 = *(const float4*)(Ap1 + k0 + 32);
            const float* Wn = Wp + (size_t)(k0 + 32) * N;
            w0 = *(const float4*)(Wn);
            w1 = *(const float4*)(Wn + N);
            w2 = *(const float4*)(Wn + 2 * (size_t)N);
            w3 = *(const float4*)(Wn + 3 * (size_t)N);
        }
        // ---- fragments (contiguous-k per lane, m92/m97 pattern)
        f16x8 fAh[2], fAl[2], fBh[4], fBl[4];
#pragma unroll
        for (int i = 0; i < 2; i++) {
            int r = (wr << 5) + (i << 4) + lrow;
            int o = lds_off(r, kby);
            fAh[i] = *(const f16x8*)(aH + o);
            fAl[i] = *(const f16x8*)(aL + o);
        }
#pragma unroll
        for (int j = 0; j < 4; j++) {
            int n = (wc << 6) + (j << 4) + lrow;
            int o = lds_off(n, kby);
            fBh[j] = *(const f16x8*)(bH + o);
            fBl[j] = *(const f16x8*)(bL + o);
        }
#pragma unroll
        for (int i = 0; i < 2; i++)
#pragma unroll
            for (int j = 0; j < 4; j++) {
                acc1[i][j] = __builtin_amdgcn_mfma_f32_16x16x32_f16(fAh[i], fBh[j], acc1[i][j], 0, 0, 0);
                acc2[i][j] = __builtin_amdgcn_mfma_f32_16x16x32_f16(fAh[i], fBl[j], acc2[i][j], 0, 0, 0);
                acc2[i][j] = __builtin_amdgcn_mfma_f32_16x16x32_f16(fAl[i], fBh[j], acc2[i][j], 0, 0, 0);
            }
    }
    // ---- epilogue: D row=(lane>>4)*4+t, col=lane&15 (m89-verified)
    const int rb = row0 + (wr << 5) + ((lane >> 4) << 2);
    const int cb = col0 + (wc << 6) + lrow;
#pragma unroll
    for (int j = 0; j < 4; j++) {
        int c = cb + (j << 4);
        float bv = bias[c];
#pragma unroll
        for (int i = 0; i < 2; i++) {
            int r = rb + (i << 4);
            float* Cp = C + (size_t)r * N + c;
            Cp[0]             = acc1[i][j][0] + acc2[i][j][0] * 0.000244140625f + bv;
            Cp[(size_t)N]     = acc1[i][j][1] + acc2[i][j][1] * 0.000244140625f + bv;
            Cp[2 * (size_t)N] = acc1[i][j][2] + acc2[i][j][2] * 0.000244140625f + bv;
            Cp[3 * (size_t)N] = acc1[i][j][3] + acc2[i][j][3] * 0.000244140625f + bv;
        }
    }
}

__global__ __launch_bounds__(256) void gemm_k(
    const float* __restrict__ A, const float* __restrict__ W,
    const float* __restrict__ bias, float* __restrict__ C, int N, int K)
{
    gemm_core(A, W, bias, C, N, K, blockIdx.y * 64, blockIdx.x * 128);
}

// fused QKV: 3x more blocks in flight than 3 serialized 96-block launches
__global__ __launch_bounds__(256) void qkv_k(
    const float* __restrict__ A,
    const float* __restrict__ Wq, const float* __restrict__ Wk, const float* __restrict__ Wv,
    const float* __restrict__ bq, const float* __restrict__ bk, const float* __restrict__ bv,
    float* __restrict__ Q, float* __restrict__ Ko, float* __restrict__ V, int Kd)
{
    int mat = blockIdx.x / 6;
    int cb  = blockIdx.x % 6;
    const float* W = (mat == 0) ? Wq : (mat == 1) ? Wk : Wv;
    const float* b = (mat == 0) ? bq : (mat == 1) ? bk : bv;
    float*       C = (mat == 0) ? Q  : (mat == 1) ? Ko : V;
    gemm_core(A, W, b, C, HH, Kd, blockIdx.y * 64, cb * 128);
}

// ---------------- embedding + LN ----------------
__global__ __launch_bounds__(256) void embed_ln_k(
    const int* __restrict__ ids, const int* __restrict__ tt,
    const float* __restrict__ we, const float* __restrict__ pe,
    const float* __restrict__ te, const float* __restrict__ g,
    const float* __restrict__ bb, float* __restrict__ out)
{
    int tok = blockIdx.x;
    int s = tok % SS;
    int id = ids[tok];
    int ty = tt[tok];
    const float* wr = we + (size_t)id * HH;
    const float* pr = pe + (size_t)s * HH;
    const float* tr = te + (size_t)ty * HH;

    float x[3];
    float sum = 0.f;
#pragma unroll
    for (int i = 0; i < 3; i++) {
        int c = threadIdx.x + i * 256;
        float v = wr[c] + pr[c] + tr[c];
        x[i] = v; sum += v;
    }
    __shared__ float red[4];
    int lane = threadIdx.x & 63, wid = threadIdx.x >> 6;
    float t1 = wave_sum(sum);
    if (lane == 0) red[wid] = t1;
    __syncthreads();
    float mean = (red[0] + red[1] + red[2] + red[3]) * (1.0f / HH);
    __syncthreads();
    float sq = 0.f;
#pragma unroll
    for (int i = 0; i < 3; i++) { x[i] -= mean; sq += x[i] * x[i]; }
    float t2 = wave_sum(sq);
    if (lane == 0) red[wid] = t2;
    __syncthreads();
    float var = (red[0] + red[1] + red[2] + red[3]) * (1.0f / HH);
    float inv = rsqrtf(var + 1e-12f);
    float* o = out + (size_t)tok * HH;
#pragma unroll
    for (int i = 0; i < 3; i++) {
        int c = threadIdx.x + i * 256;
        o[c] = g[c] * x[i] * inv + bb[c];
    }
}

// ---------------- residual add + LN (in place on h) ----------------
__global__ __launch_bounds__(256) void resln_k(
    float* __restrict__ h, const float* __restrict__ p,
    const float* __restrict__ g, const float* __restrict__ bb)
{
    int tok = blockIdx.x;
    float* hr = h + (size_t)tok * HH;
    const float* pr = p + (size_t)tok * HH;
    float x[3];
    float sum = 0.f;
#pragma unroll
    for (int i = 0; i < 3; i++) {
        int c = threadIdx.x + i * 256;
        float v = hr[c] + pr[c];
        x[i] = v; sum += v;
    }
    __shared__ float red[4];
    int lane = threadIdx.x & 63, wid = threadIdx.x >> 6;
    float t1 = wave_sum(sum);
    if (lane == 0) red[wid] = t1;
    __syncthreads();
    float mean = (red[0] + red[1] + red[2] + red[3]) * (1.0f / HH);
    __syncthreads();
    float sq = 0.f;
#pragma unroll
    for (int i = 0; i < 3; i++) { x[i] -= mean; sq += x[i] * x[i]; }
    float t2 = wave_sum(sq);
    if (lane == 0) red[wid] = t2;
    __syncthreads();
    float var = (red[0] + red[1] + red[2] + red[3]) * (1.0f / HH);
    float inv = rsqrtf(var + 1e-12f);
#pragma unroll
    for (int i = 0; i < 3; i++) {
        int c = threadIdx.x + i * 256;
        hr[c] = g[c] * x[i] * inv + bb[c];
    }
}

// ---------------- attention scores: Sc[b,h,q,k] = Q.K/8 + bias ----------------
__global__ __launch_bounds__(256) void attn_scores_k(
    const float* __restrict__ Qb, const float* __restrict__ Kb,
    const int* __restrict__ mask, float* __restrict__ Sc)
{
    int bh = blockIdx.x;
    int b = bh / NHD, hh = bh % NHD;
    __shared__ float Ks[SS][DHD + 1];
    for (int i = threadIdx.x; i < SS * DHD; i += 256) {
        int k = i >> 6, d = i & 63;
        Ks[k][d] = Kb[(size_t)(b * SS + k) * HH + hh * DHD + d];
    }
    __syncthreads();
    int kk = threadIdx.x & 127;
    int qh = threadIdx.x >> 7;  // 0..1
    float biasv = (1.0f - (float)mask[b * SS + kk]) * -1e9f;
    for (int q = qh; q < SS; q += 2) {
        const float* Qr = Qb + (size_t)(b * SS + q) * HH + hh * DHD;
        float acc = 0.f;
#pragma unroll 8
        for (int d = 0; d < DHD; d++) acc += Qr[d] * Ks[kk][d];
        Sc[((size_t)bh * SS + q) * SS + kk] = acc * 0.125f + biasv;
    }
}

// ---------------- row softmax over 128 (one wave per row) ----------------
__global__ __launch_bounds__(64) void softmax_k(float* __restrict__ Sc)
{
    size_t row = blockIdx.x;
    float* p = Sc + row * SS;
    int t = threadIdx.x;
    float a = p[t], b = p[t + 64];
    float mx = fmaxf(a, b);
#pragma unroll
    for (int o = 32; o > 0; o >>= 1) mx = fmaxf(mx, __shfl_down(mx, o, 64));
    mx = __shfl(mx, 0, 64);
    float ea = expf(a - mx), eb = expf(b - mx);
    float sm = ea + eb;
#pragma unroll
    for (int o = 32; o > 0; o >>= 1) sm += __shfl_down(sm, o, 64);
    sm = __shfl(sm, 0, 64);
    float inv = 1.0f / sm;
    p[t] = ea * inv;
    p[t + 64] = eb * inv;
}

// ---------------- ctx[b,q,h,d] = sum_k P[b,h,q,k] V[b,k,h,d] ----------------
__global__ __launch_bounds__(256) void attn_ctx_k(
    const float* __restrict__ Sc, const float* __restrict__ Vb,
    float* __restrict__ Cb)
{
    int bh = blockIdx.x;
    int b = bh / NHD, hh = bh % NHD;
    __shared__ float Vs[SS][DHD];   // stride 64: 2-way bank alias = free
    for (int i = threadIdx.x; i < SS * DHD; i += 256) {
        int k = i >> 6, d = i & 63;
        Vs[k][d] = Vb[(size_t)(b * SS + k) * HH + hh * DHD + d];
    }
    __syncthreads();
    int d = threadIdx.x & 63;
    int qg = threadIdx.x >> 6;  // 0..3
    for (int q = qg; q < SS; q += 4) {
        const float* P = Sc + ((size_t)bh * SS + q) * SS;
        float acc = 0.f;
#pragma unroll 8
        for (int k = 0; k < SS; k++) acc += P[k] * Vs[k][d];
        Cb[(size_t)(b * SS + q) * HH + hh * DHD + d] = acc;
    }
}

// ---------------- exact GELU ----------------
__global__ __launch_bounds__(256) void gelu_k(float* __restrict__ x, int n4)
{
    int i = blockIdx.x * 256 + threadIdx.x;
    if (i < n4) {
        float4 v = ((float4*)x)[i];
        v.x = 0.5f * v.x * (1.f + erff(v.x * 0.70710678118654752f));
        v.y = 0.5f * v.y * (1.f + erff(v.y * 0.70710678118654752f));
        v.z = 0.5f * v.z * (1.f + erff(v.z * 0.70710678118654752f));
        v.w = 0.5f * v.w * (1.f + erff(v.w * 0.70710678118654752f));
        ((float4*)x)[i] = v;
    }
}

// ---------------- emissions: em = h @ fc_w + fc_b  (N=9) ----------------
__global__ __launch_bounds__(64) void emissions_k(
    const float* __restrict__ h, const float* __restrict__ fcw,
    const float* __restrict__ fcb, float* __restrict__ em)
{
    int tok = blockIdx.x;
    const float* hr = h + (size_t)tok * HH;
    float acc[NT];
#pragma unroll
    for (int t = 0; t < NT; t++) acc[t] = 0.f;
    for (int c = threadIdx.x; c < HH; c += 64) {
        float x = hr[c];
#pragma unroll
        for (int t = 0; t < NT; t++) acc[t] += x * fcw[c * NT + t];
    }
#pragma unroll
    for (int t = 0; t < NT; t++) {
        float v = wave_sum(acc[t]);
        if (threadIdx.x == 0) em[(size_t)tok * NT + t] = v + fcb[t];
    }
}

// ---------------- CRF forward (one block per batch element) ----------------
__global__ __launch_bounds__(64) void crf_k(
    const float* __restrict__ em, const int* __restrict__ tags,
    const int* __restrict__ mask, const float* __restrict__ startv,
    const float* __restrict__ endv, const float* __restrict__ trans,
    float* __restrict__ llh)
{
    int b = blockIdx.x;
    const float* E = em + (size_t)b * SS * NT;
    __shared__ float alpha[NT];
    __shared__ float nalpha[NT];
    int j = threadIdx.x;
    if (j < NT) alpha[j] = startv[j] + E[j];
    __syncthreads();
    for (int t = 1; t < SS; t++) {
        if (j < NT) {
            int m = mask[b * SS + t];
            float mx = -1e30f;
#pragma unroll
            for (int i = 0; i < NT; i++) mx = fmaxf(mx, alpha[i] + trans[i * NT + j]);
            float sm = 0.f;
#pragma unroll
            for (int i = 0; i < NT; i++) sm += expf(alpha[i] + trans[i * NT + j] - mx);
            float nx = mx + logf(sm) + E[t * NT + j];
            nalpha[j] = m ? nx : alpha[j];
        }
        __syncthreads();
        if (j < NT) alpha[j] = nalpha[j];
        __syncthreads();
    }
    if (j == 0) {
        float mx = -1e30f;
        for (int i = 0; i < NT; i++) mx = fmaxf(mx, alpha[i] + endv[i]);
        float sm = 0.f;
        for (int i = 0; i < NT; i++) sm += expf(alpha[i] + endv[i] - mx);
        float logZ = mx + logf(sm);

        const int* tg = tags + b * SS;
        float num = startv[tg[0]] + E[tg[0]];
        for (int t = 1; t < SS; t++) {
            float msk = (float)mask[b * SS + t];
            num += (trans[tg[t - 1] * NT + tg[t]] + E[t * NT + tg[t]]) * msk;
        }
        int cnt = 0;
        for (int t = 0; t < SS; t++) cnt += mask[b * SS + t];
        num += endv[tg[cnt - 1]];
        llh[b] = num - logZ;
    }
}

__global__ __launch_bounds__(64) void loss_k(const float* __restrict__ llh, float* __restrict__ out)
{
    if (threadIdx.x == 0) {
        float s = 0.f;
        for (int b = 0; b < NB; b++) s += llh[b];
        out[0] = -s / NB;
    }
}

extern "C" void kernel_launch(void* const* d_in, const int* in_sizes, int n_in,
                              void* d_out, int out_size, void* d_ws, size_t ws_size,
                              hipStream_t stream)
{
    const int* ids  = (const int*)d_in[0];
    const int* mask = (const int*)d_in[1];
    const int* tt   = (const int*)d_in[2];
    const int* tags = (const int*)d_in[3];
    const float* wemb = (const float*)d_in[4];
    const float* pemb = (const float*)d_in[5];
    const float* temb = (const float*)d_in[6];
    const float* elg  = (const float*)d_in[7];
    const float* elb  = (const float*)d_in[8];
    const float* Wq = (const float*)d_in[9];
    const float* bq = (const float*)d_in[10];
    const float* Wk = (const float*)d_in[11];
    const float* bk = (const float*)d_in[12];
    const float* Wv = (const float*)d_in[13];
    const float* bv = (const float*)d_in[14];
    const float* Wo = (const float*)d_in[15];
    const float* bo = (const float*)d_in[16];
    const float* g1 = (const float*)d_in[17];
    const float* b1 = (const float*)d_in[18];
    const float* Wi = (const float*)d_in[19];
    const float* bi = (const float*)d_in[20];
    const float* Wo2 = (const float*)d_in[21];
    const float* bo2 = (const float*)d_in[22];
    const float* g2 = (const float*)d_in[23];
    const float* b2 = (const float*)d_in[24];
    const float* fcw = (const float*)d_in[25];
    const float* fcb = (const float*)d_in[26];
    const float* cst = (const float*)d_in[27];
    const float* cen = (const float*)d_in[28];
    const float* ctr = (const float*)d_in[29];

    float* ws = (float*)d_ws;
    const size_t TH = (size_t)TOK * HH;
    float* h  = ws;
    float* qb = h + TH;
    float* kb = qb + TH;
    float* vb = kb + TH;
    float* ob = vb + TH;                                  // ctx / proj out
    float* sc = ob + TH;                                  // (B,NH,S,S)
    float* ff = sc + (size_t)NB * NHD * SS * SS;          // (TOK,FF)
    float* llh = ff + (size_t)TOK * FFD;

    float* emis = (float*)d_out;
    float* loss = emis + (size_t)TOK * NT;

    embed_ln_k<<<TOK, 256, 0, stream>>>(ids, tt, wemb, pemb, temb, elg, elb, h);

    dim3 gQKV(3 * (HH / 128), TOK / 64);   // (18, 32)
    dim3 gH(HH / 128, TOK / 64);           // (6, 32)
    dim3 gF(FFD / 128, TOK / 64);          // (24, 32)

    for (int l = 0; l < NLAY; l++) {
        const float* wql = Wq + (size_t)l * HH * HH;  const float* bql = bq + (size_t)l * HH;
        const float* wkl = Wk + (size_t)l * HH * HH;  const float* bkl = bk + (size_t)l * HH;
        const float* wvl = Wv + (size_t)l * HH * HH;  const float* bvl = bv + (size_t)l * HH;
        const float* wol = Wo + (size_t)l * HH * HH;  const float* bol = bo + (size_t)l * HH;
        const float* g1l = g1 + (size_t)l * HH;       const float* b1l = b1 + (size_t)l * HH;
        const float* wil = Wi + (size_t)l * HH * FFD; const float* bil = bi + (size_t)l * FFD;
        const float* w2l = Wo2 + (size_t)l * FFD * HH; const float* b2l_ = bo2 + (size_t)l * HH;
        const float* g2l = g2 + (size_t)l * HH;       const float* b2l = b2 + (size_t)l * HH;

        qkv_k<<<gQKV, 256, 0, stream>>>(h, wql, wkl, wvl, bql, bkl, bvl, qb, kb, vb, HH);
        attn_scores_k<<<NB * NHD, 256, 0, stream>>>(qb, kb, mask, sc);
        softmax_k<<<NB * NHD * SS, 64, 0, stream>>>(sc);
        attn_ctx_k<<<NB * NHD, 256, 0, stream>>>(sc, vb, ob);
        gemm_k<<<gH, 256, 0, stream>>>(ob, wol, bol, qb, HH, HH);
        resln_k<<<TOK, 256, 0, stream>>>(h, qb, g1l, b1l);
        gemm_k<<<gF, 256, 0, stream>>>(h, wil, bil, ff, FFD, HH);
        gelu_k<<<(TOK * FFD / 4 + 255) / 256, 256, 0, stream>>>(ff, TOK * FFD / 4);
        gemm_k<<<gH, 256, 0, stream>>>(ff, w2l, b2l_, qb, HH, FFD);
        resln_k<<<TOK, 256, 0, stream>>>(h, qb, g2l, b2l);
    }

    emissions_k<<<TOK, 64, 0, stream>>>(h, fcw, fcb, emis);
    crf_k<<<NB, 64, 0, stream>>>(emis, tags, mask, cst, cen, ctr, llh);
    loss_k<<<1, 64, 0, stream>>>(llh, loss);
}

// Round 4
// 5056.684 us; speedup vs baseline: 2.0930x; 1.2247x over previous
//
#include <hip/hip_runtime.h>
#include <math.h>

// Problem constants (BertCrf)
#define NB   16      // batch
#define SS   128     // seq len
#define HH   768     // hidden
#define NHD  12      // heads
#define DHD  64      // head dim
#define FFD  3072    // ffn dim
#define NLAY 12      // layers
#define NT   9       // tags
#define TOK  (NB*SS) // 2048 tokens

typedef __attribute__((ext_vector_type(4))) float    f32x4;
typedef __attribute__((ext_vector_type(8))) _Float16 f16x8;

__device__ __forceinline__ float wave_sum(float v) {
#pragma unroll
    for (int o = 32; o > 0; o >>= 1) v += __shfl_down(v, o, 64);
    return v;
}

// LDS layout: row-major [row][32 k] fp16 (64 B/row), XOR swizzle on the 16B
// slot so fragment ds_read_b128 across 16 rows is 2-way (free) not 16-way.
__device__ __forceinline__ int lds_off(int row, int kbyte) {
    return (row << 6) + (kbyte ^ (((row >> 1) & 3) << 4));
}

// ---------------- weight convert + transpose kernel ----------------
// W[K][N] fp32 -> WtH/WtL [N][K] f16 planes (Markidis split: x = h + l*2^-12)
// blockIdx.z = layer (stride K*N both sides). Tiled 32x32 via LDS.
__global__ __launch_bounds__(256) void wconv_k(
    const float* __restrict__ W, _Float16* __restrict__ WtH,
    _Float16* __restrict__ WtL, int K, int N)
{
    __shared__ _Float16 tH[32][33];
    __shared__ _Float16 tL[32][33];
    const size_t lstr = (size_t)K * N;
    const float* Wl = W + lstr * blockIdx.z;
    _Float16* oH = WtH + lstr * blockIdx.z;
    _Float16* oL = WtL + lstr * blockIdx.z;
    int n0 = blockIdx.x * 32, k0 = blockIdx.y * 32;
    int tn = threadIdx.x & 31;
    int tk = threadIdx.x >> 5;          // 0..7
#pragma unroll
    for (int i = 0; i < 4; i++) {
        int k = tk + i * 8;
        float v = Wl[(size_t)(k0 + k) * N + n0 + tn];
        _Float16 hh = (_Float16)v;
        tH[k][tn] = hh;
        tL[k][tn] = (_Float16)((v - (float)hh) * 4096.0f);
    }
    __syncthreads();
    int wk = threadIdx.x & 31;
    int wn = threadIdx.x >> 5;
#pragma unroll
    for (int i = 0; i < 4; i++) {
        int n = wn + i * 8;
        oH[(size_t)(n0 + n) * K + k0 + wk] = tH[wk][n];
        oL[(size_t)(n0 + n) * K + k0 + wk] = tL[wk][n];
    }
}

// ---------------- split-f16 MFMA GEMM core (pre-converted planes) ----------
// C[M x N] = A[M x K] @ W[K x N] + bias, fp32-grade accuracy.
// A planes [M][K] f16 hi/lo; W planes pre-transposed [N][K] f16 hi/lo.
// Tile 64(M) x 128(N), BK=32, 256 threads = 4 waves (2x2), wave = 32x64 out.
// EPI 0: C fp32.  EPI 1: gelu(C) -> gH/gL planes (no fp32 out).
template<int EPI>
__device__ __forceinline__ void gemm_core(
    const _Float16* __restrict__ aHp, const _Float16* __restrict__ aLp,
    const _Float16* __restrict__ bHp, const _Float16* __restrict__ bLp,
    const float* __restrict__ bias, float* __restrict__ C,
    _Float16* __restrict__ gH, _Float16* __restrict__ gL,
    int N, int K, int row0, int col0)
{
    __shared__ __align__(16) char lds[24576];
    char* aH = lds;             // 64 rows * 64B
    char* aL = lds + 4096;
    char* bH = lds + 8192;      // 128 rows * 64B
    char* bL = lds + 16384;

    const int tid  = threadIdx.x;
    const int lane = tid & 63;
    const int wid  = tid >> 6;
    const int wr   = wid >> 1;          // wave row 0..1
    const int wc   = wid & 1;           // wave col 0..1
    const int lrow = lane & 15;
    const int kby  = (lane >> 4) << 4;  // frag k byte offset

    // staging: thread t covers row = t>>2 (0..63), k-slot = t&3 (8 f16 each)
    const int srow  = tid >> 2;
    const int sslot = (tid & 3) << 4;   // LDS byte slot
    const int sk    = (tid & 3) << 3;   // k element offset

    const _Float16* ApH  = aHp + (size_t)(row0 + srow) * K + sk;
    const _Float16* ApL  = aLp + (size_t)(row0 + srow) * K + sk;
    const _Float16* BpH0 = bHp + (size_t)(col0 + srow) * K + sk;
    const _Float16* BpL0 = bLp + (size_t)(col0 + srow) * K + sk;
    const _Float16* BpH1 = bHp + (size_t)(col0 + 64 + srow) * K + sk;
    const _Float16* BpL1 = bLp + (size_t)(col0 + 64 + srow) * K + sk;

    f32x4 acc1[2][4] = {};
    f32x4 acc2[2][4] = {};

    // prefetch tile 0 (pure 16B copies, no conversion)
    f16x8 ra_h = *(const f16x8*)ApH;
    f16x8 ra_l = *(const f16x8*)ApL;
    f16x8 rb0h = *(const f16x8*)BpH0;
    f16x8 rb0l = *(const f16x8*)BpL0;
    f16x8 rb1h = *(const f16x8*)BpH1;
    f16x8 rb1l = *(const f16x8*)BpL1;

    for (int k0 = 0; k0 < K; k0 += 32) {
        __syncthreads();   // previous iter's LDS reads complete
        *(f16x8*)(aH + lds_off(srow, sslot))      = ra_h;
        *(f16x8*)(aL + lds_off(srow, sslot))      = ra_l;
        *(f16x8*)(bH + lds_off(srow, sslot))      = rb0h;
        *(f16x8*)(bL + lds_off(srow, sslot))      = rb0l;
        *(f16x8*)(bH + lds_off(64 + srow, sslot)) = rb1h;
        *(f16x8*)(bL + lds_off(64 + srow, sslot)) = rb1l;
        __syncthreads();
        // prefetch next K tile (hides HBM/L2 latency under MFMA phase)
        if (k0 + 32 < K) {
            ra_h = *(const f16x8*)(ApH  + k0 + 32);
            ra_l = *(const f16x8*)(ApL  + k0 + 32);
            rb0h = *(const f16x8*)(BpH0 + k0 + 32);
            rb0l = *(const f16x8*)(BpL0 + k0 + 32);
            rb1h = *(const f16x8*)(BpH1 + k0 + 32);
            rb1l = *(const f16x8*)(BpL1 + k0 + 32);
        }
        // fragments (contiguous-k per lane, m92/m97 pattern)
        f16x8 fAh[2], fAl[2], fBh[4], fBl[4];
#pragma unroll
        for (int i = 0; i < 2; i++) {
            int r = (wr << 5) + (i << 4) + lrow;
            int o = lds_off(r, kby);
            fAh[i] = *(const f16x8*)(aH + o);
            fAl[i] = *(const f16x8*)(aL + o);
        }
#pragma unroll
        for (int j = 0; j < 4; j++) {
            int n = (wc << 6) + (j << 4) + lrow;
            int o = lds_off(n, kby);
            fBh[j] = *(const f16x8*)(bH + o);
            fBl[j] = *(const f16x8*)(bL + o);
        }
#pragma unroll
        for (int i = 0; i < 2; i++)
#pragma unroll
            for (int j = 0; j < 4; j++) {
                acc1[i][j] = __builtin_amdgcn_mfma_f32_16x16x32_f16(fAh[i], fBh[j], acc1[i][j], 0, 0, 0);
                acc2[i][j] = __builtin_amdgcn_mfma_f32_16x16x32_f16(fAh[i], fBl[j], acc2[i][j], 0, 0, 0);
                acc2[i][j] = __builtin_amdgcn_mfma_f32_16x16x32_f16(fAl[i], fBh[j], acc2[i][j], 0, 0, 0);
            }
    }
    // epilogue: D row=(lane>>4)*4+t, col=lane&15 (m89-verified)
    const int rb = row0 + (wr << 5) + ((lane >> 4) << 2);
    const int cb = col0 + (wc << 6) + lrow;
#pragma unroll
    for (int j = 0; j < 4; j++) {
        int c = cb + (j << 4);
        float bv = bias[c];
#pragma unroll
        for (int i = 0; i < 2; i++) {
            int r = rb + (i << 4);
#pragma unroll
            for (int t = 0; t < 4; t++) {
                float v = acc1[i][j][t] + acc2[i][j][t] * 0.000244140625f + bv;
                if (EPI == 0) {
                    C[(size_t)(r + t) * N + c] = v;
                } else {
                    v = 0.5f * v * (1.f + erff(v * 0.70710678118654752f));
                    _Float16 vh = (_Float16)v;
                    gH[(size_t)(r + t) * N + c] = vh;
                    gL[(size_t)(r + t) * N + c] = (_Float16)((v - (float)vh) * 4096.0f);
                }
            }
        }
    }
}

template<int EPI>
__global__ __launch_bounds__(256) void gemm_k(
    const _Float16* __restrict__ aH, const _Float16* __restrict__ aL,
    const _Float16* __restrict__ bH, const _Float16* __restrict__ bL,
    const float* __restrict__ bias, float* __restrict__ C,
    _Float16* __restrict__ gH, _Float16* __restrict__ gL, int N, int K)
{
    gemm_core<EPI>(aH, aL, bH, bL, bias, C, gH, gL, N, K,
                   blockIdx.y * 64, blockIdx.x * 128);
}

// fused QKV from h-planes
__global__ __launch_bounds__(256) void qkv_k(
    const _Float16* __restrict__ aH, const _Float16* __restrict__ aL,
    const _Float16* __restrict__ qH, const _Float16* __restrict__ qL,
    const _Float16* __restrict__ kH, const _Float16* __restrict__ kL,
    const _Float16* __restrict__ vH, const _Float16* __restrict__ vL,
    const float* __restrict__ bq, const float* __restrict__ bk,
    const float* __restrict__ bv,
    float* __restrict__ Q, float* __restrict__ Ko, float* __restrict__ V)
{
    int mat = blockIdx.x / 6;
    int cb  = blockIdx.x % 6;
    const _Float16* bH = (mat == 0) ? qH : (mat == 1) ? kH : vH;
    const _Float16* bL = (mat == 0) ? qL : (mat == 1) ? kL : vL;
    const float* bias  = (mat == 0) ? bq : (mat == 1) ? bk : bv;
    float* C           = (mat == 0) ? Q  : (mat == 1) ? Ko : V;
    gemm_core<0>(aH, aL, bH, bL, bias, C, nullptr, nullptr, HH, HH,
                 blockIdx.y * 64, cb * 128);
}

// ---------------- embedding + LN (+ h planes) ----------------
__global__ __launch_bounds__(256) void embed_ln_k(
    const int* __restrict__ ids, const int* __restrict__ tt,
    const float* __restrict__ we, const float* __restrict__ pe,
    const float* __restrict__ te, const float* __restrict__ g,
    const float* __restrict__ bb, float* __restrict__ out,
    _Float16* __restrict__ pH, _Float16* __restrict__ pL)
{
    int tok = blockIdx.x;
    int s = tok % SS;
    int id = ids[tok];
    int ty = tt[tok];
    const float* wr = we + (size_t)id * HH;
    const float* pr = pe + (size_t)s * HH;
    const float* tr = te + (size_t)ty * HH;

    float x[3];
    float sum = 0.f;
#pragma unroll
    for (int i = 0; i < 3; i++) {
        int c = threadIdx.x + i * 256;
        float v = wr[c] + pr[c] + tr[c];
        x[i] = v; sum += v;
    }
    __shared__ float red[4];
    int lane = threadIdx.x & 63, wid = threadIdx.x >> 6;
    float t1 = wave_sum(sum);
    if (lane == 0) red[wid] = t1;
    __syncthreads();
    float mean = (red[0] + red[1] + red[2] + red[3]) * (1.0f / HH);
    __syncthreads();
    float sq = 0.f;
#pragma unroll
    for (int i = 0; i < 3; i++) { x[i] -= mean; sq += x[i] * x[i]; }
    float t2 = wave_sum(sq);
    if (lane == 0) red[wid] = t2;
    __syncthreads();
    float var = (red[0] + red[1] + red[2] + red[3]) * (1.0f / HH);
    float inv = rsqrtf(var + 1e-12f);
    float* o = out + (size_t)tok * HH;
    _Float16* oh = pH + (size_t)tok * HH;
    _Float16* ol = pL + (size_t)tok * HH;
#pragma unroll
    for (int i = 0; i < 3; i++) {
        int c = threadIdx.x + i * 256;
        float v = g[c] * x[i] * inv + bb[c];
        o[c] = v;
        _Float16 vh = (_Float16)v;
        oh[c] = vh;
        ol[c] = (_Float16)((v - (float)vh) * 4096.0f);
    }
}

// ---------------- residual add + LN (in place on h, + planes) -------------
__global__ __launch_bounds__(256) void resln_k(
    float* __restrict__ h, const float* __restrict__ p,
    const float* __restrict__ g, const float* __restrict__ bb,
    _Float16* __restrict__ pH, _Float16* __restrict__ pL)
{
    int tok = blockIdx.x;
    float* hr = h + (size_t)tok * HH;
    const float* pr = p + (size_t)tok * HH;
    float x[3];
    float sum = 0.f;
#pragma unroll
    for (int i = 0; i < 3; i++) {
        int c = threadIdx.x + i * 256;
        float v = hr[c] + pr[c];
        x[i] = v; sum += v;
    }
    __shared__ float red[4];
    int lane = threadIdx.x & 63, wid = threadIdx.x >> 6;
    float t1 = wave_sum(sum);
    if (lane == 0) red[wid] = t1;
    __syncthreads();
    float mean = (red[0] + red[1] + red[2] + red[3]) * (1.0f / HH);
    __syncthreads();
    float sq = 0.f;
#pragma unroll
    for (int i = 0; i < 3; i++) { x[i] -= mean; sq += x[i] * x[i]; }
    float t2 = wave_sum(sq);
    if (lane == 0) red[wid] = t2;
    __syncthreads();
    float var = (red[0] + red[1] + red[2] + red[3]) * (1.0f / HH);
    float inv = rsqrtf(var + 1e-12f);
    _Float16* oh = pH + (size_t)tok * HH;
    _Float16* ol = pL + (size_t)tok * HH;
#pragma unroll
    for (int i = 0; i < 3; i++) {
        int c = threadIdx.x + i * 256;
        float v = g[c] * x[i] * inv + bb[c];
        hr[c] = v;
        _Float16 vh = (_Float16)v;
        oh[c] = vh;
        ol[c] = (_Float16)((v - (float)vh) * 4096.0f);
    }
}

// ---------------- attention scores: Sc[b,h,q,k] = Q.K/8 + bias -------------
__global__ __launch_bounds__(256) void attn_scores_k(
    const float* __restrict__ Qb, const float* __restrict__ Kb,
    const int* __restrict__ mask, float* __restrict__ Sc)
{
    int bh = blockIdx.x;
    int b = bh / NHD, hh = bh % NHD;
    __shared__ float Ks[SS][DHD + 1];
    for (int i = threadIdx.x; i < SS * DHD; i += 256) {
        int k = i >> 6, d = i & 63;
        Ks[k][d] = Kb[(size_t)(b * SS + k) * HH + hh * DHD + d];
    }
    __syncthreads();
    int kk = threadIdx.x & 127;
    int qh = threadIdx.x >> 7;  // 0..1
    float biasv = (1.0f - (float)mask[b * SS + kk]) * -1e9f;
    for (int q = qh; q < SS; q += 2) {
        const float* Qr = Qb + (size_t)(b * SS + q) * HH + hh * DHD;
        float acc = 0.f;
#pragma unroll 8
        for (int d = 0; d < DHD; d++) acc += Qr[d] * Ks[kk][d];
        Sc[((size_t)bh * SS + q) * SS + kk] = acc * 0.125f + biasv;
    }
}

// ---------------- row softmax over 128 (one wave per row) ----------------
__global__ __launch_bounds__(64) void softmax_k(float* __restrict__ Sc)
{
    size_t row = blockIdx.x;
    float* p = Sc + row * SS;
    int t = threadIdx.x;
    float a = p[t], b = p[t + 64];
    float mx = fmaxf(a, b);
#pragma unroll
    for (int o = 32; o > 0; o >>= 1) mx = fmaxf(mx, __shfl_down(mx, o, 64));
    mx = __shfl(mx, 0, 64);
    float ea = expf(a - mx), eb = expf(b - mx);
    float sm = ea + eb;
#pragma unroll
    for (int o = 32; o > 0; o >>= 1) sm += __shfl_down(sm, o, 64);
    sm = __shfl(sm, 0, 64);
    float inv = 1.0f / sm;
    p[t] = ea * inv;
    p[t + 64] = eb * inv;
}

// -------- ctx planes: ctxP[b,q,h,d] = split(sum_k P[b,h,q,k] V[b,k,h,d]) ---
__global__ __launch_bounds__(256) void attn_ctx_k(
    const float* __restrict__ Sc, const float* __restrict__ Vb,
    _Float16* __restrict__ oPH, _Float16* __restrict__ oPL)
{
    int bh = blockIdx.x;
    int b = bh / NHD, hh = bh % NHD;
    __shared__ float Vs[SS][DHD];   // stride 64: 2-way bank alias = free
    for (int i = threadIdx.x; i < SS * DHD; i += 256) {
        int k = i >> 6, d = i & 63;
        Vs[k][d] = Vb[(size_t)(b * SS + k) * HH + hh * DHD + d];
    }
    __syncthreads();
    int d = threadIdx.x & 63;
    int qg = threadIdx.x >> 6;  // 0..3
    for (int q = qg; q < SS; q += 4) {
        const float* P = Sc + ((size_t)bh * SS + q) * SS;
        float acc = 0.f;
#pragma unroll 8
        for (int k = 0; k < SS; k++) acc += P[k] * Vs[k][d];
        size_t o = (size_t)(b * SS + q) * HH + hh * DHD + d;
        _Float16 ch = (_Float16)acc;
        oPH[o] = ch;
        oPL[o] = (_Float16)((acc - (float)ch) * 4096.0f);
    }
}

// ---------------- emissions: em = h @ fc_w + fc_b  (N=9) ----------------
__global__ __launch_bounds__(64) void emissions_k(
    const float* __restrict__ h, const float* __restrict__ fcw,
    const float* __restrict__ fcb, float* __restrict__ em)
{
    int tok = blockIdx.x;
    const float* hr = h + (size_t)tok * HH;
    float acc[NT];
#pragma unroll
    for (int t = 0; t < NT; t++) acc[t] = 0.f;
    for (int c = threadIdx.x; c < HH; c += 64) {
        float x = hr[c];
#pragma unroll
        for (int t = 0; t < NT; t++) acc[t] += x * fcw[c * NT + t];
    }
#pragma unroll
    for (int t = 0; t < NT; t++) {
        float v = wave_sum(acc[t]);
        if (threadIdx.x == 0) em[(size_t)tok * NT + t] = v + fcb[t];
    }
}

// ---------------- CRF forward (one block per batch element) ----------------
__global__ __launch_bounds__(64) void crf_k(
    const float* __restrict__ em, const int* __restrict__ tags,
    const int* __restrict__ mask, const float* __restrict__ startv,
    const float* __restrict__ endv, const float* __restrict__ trans,
    float* __restrict__ llh)
{
    int b = blockIdx.x;
    const float* E = em + (size_t)b * SS * NT;
    __shared__ float alpha[NT];
    __shared__ float nalpha[NT];
    int j = threadIdx.x;
    if (j < NT) alpha[j] = startv[j] + E[j];
    __syncthreads();
    for (int t = 1; t < SS; t++) {
        if (j < NT) {
            int m = mask[b * SS + t];
            float mx = -1e30f;
#pragma unroll
            for (int i = 0; i < NT; i++) mx = fmaxf(mx, alpha[i] + trans[i * NT + j]);
            float sm = 0.f;
#pragma unroll
            for (int i = 0; i < NT; i++) sm += expf(alpha[i] + trans[i * NT + j] - mx);
            float nx = mx + logf(sm) + E[t * NT + j];
            nalpha[j] = m ? nx : alpha[j];
        }
        __syncthreads();
        if (j < NT) alpha[j] = nalpha[j];
        __syncthreads();
    }
    if (j == 0) {
        float mx = -1e30f;
        for (int i = 0; i < NT; i++) mx = fmaxf(mx, alpha[i] + endv[i]);
        float sm = 0.f;
        for (int i = 0; i < NT; i++) sm += expf(alpha[i] + endv[i] - mx);
        float logZ = mx + logf(sm);

        const int* tg = tags + b * SS;
        float num = startv[tg[0]] + E[tg[0]];
        for (int t = 1; t < SS; t++) {
            float msk = (float)mask[b * SS + t];
            num += (trans[tg[t - 1] * NT + tg[t]] + E[t * NT + tg[t]]) * msk;
        }
        int cnt = 0;
        for (int t = 0; t < SS; t++) cnt += mask[b * SS + t];
        num += endv[tg[cnt - 1]];
        llh[b] = num - logZ;
    }
}

__global__ __launch_bounds__(64) void loss_k(const float* __restrict__ llh, float* __restrict__ out)
{
    if (threadIdx.x == 0) {
        float s = 0.f;
        for (int b = 0; b < NB; b++) s += llh[b];
        out[0] = -s / NB;
    }
}

extern "C" void kernel_launch(void* const* d_in, const int* in_sizes, int n_in,
                              void* d_out, int out_size, void* d_ws, size_t ws_size,
                              hipStream_t stream)
{
    const int* ids  = (const int*)d_in[0];
    const int* mask = (const int*)d_in[1];
    const int* tt   = (const int*)d_in[2];
    const int* tags = (const int*)d_in[3];
    const float* wemb = (const float*)d_in[4];
    const float* pemb = (const float*)d_in[5];
    const float* temb = (const float*)d_in[6];
    const float* elg  = (const float*)d_in[7];
    const float* elb  = (const float*)d_in[8];
    const float* Wq = (const float*)d_in[9];
    const float* bq = (const float*)d_in[10];
    const float* Wk = (const float*)d_in[11];
    const float* bk = (const float*)d_in[12];
    const float* Wv = (const float*)d_in[13];
    const float* bv = (const float*)d_in[14];
    const float* Wo = (const float*)d_in[15];
    const float* bo = (const float*)d_in[16];
    const float* g1 = (const float*)d_in[17];
    const float* b1 = (const float*)d_in[18];
    const float* Wi = (const float*)d_in[19];
    const float* bi = (const float*)d_in[20];
    const float* Wo2 = (const float*)d_in[21];
    const float* bo2 = (const float*)d_in[22];
    const float* g2 = (const float*)d_in[23];
    const float* b2 = (const float*)d_in[24];
    const float* fcw = (const float*)d_in[25];
    const float* fcb = (const float*)d_in[26];
    const float* cst = (const float*)d_in[27];
    const float* cen = (const float*)d_in[28];
    const float* ctr = (const float*)d_in[29];

    float* ws = (float*)d_ws;
    const size_t TH = (size_t)TOK * HH;     // 1.57M
    const size_t TF = (size_t)TOK * FFD;    // 6.29M
    float* h  = ws;
    float* qb = h + TH;
    float* kb = qb + TH;
    float* vb = kb + TH;
    float* sc = vb + TH;                                  // (B,NH,S,S)
    float* llh = sc + (size_t)NB * NHD * SS * SS;         // NB floats

    // f16 plane region (16B-aligned: all offsets are multiples of 256B)
    _Float16* fp = (_Float16*)(llh + 64);
    _Float16* hPH = fp; fp += TH;   _Float16* hPL = fp; fp += TH;
    _Float16* oPH = fp; fp += TH;   _Float16* oPL = fp; fp += TH;
    _Float16* fPH = fp; fp += TF;   _Float16* fPL = fp; fp += TF;
    const size_t WH2 = (size_t)NLAY * HH * HH;
    const size_t WHF = (size_t)NLAY * HH * FFD;
    _Float16* WqH = fp; fp += WH2;  _Float16* WqL = fp; fp += WH2;
    _Float16* WkH = fp; fp += WH2;  _Float16* WkL = fp; fp += WH2;
    _Float16* WvH = fp; fp += WH2;  _Float16* WvL = fp; fp += WH2;
    _Float16* WoH = fp; fp += WH2;  _Float16* WoL = fp; fp += WH2;
    _Float16* WiH = fp; fp += WHF;  _Float16* WiL = fp; fp += WHF;
    _Float16* W2H = fp; fp += WHF;  _Float16* W2L = fp; fp += WHF;

    float* emis = (float*)d_out;
    float* loss = emis + (size_t)TOK * NT;

    // ---- one-time (per call) weight convert+transpose to f16 planes ----
    wconv_k<<<dim3(HH / 32, HH / 32, NLAY), 256, 0, stream>>>(Wq, WqH, WqL, HH, HH);
    wconv_k<<<dim3(HH / 32, HH / 32, NLAY), 256, 0, stream>>>(Wk, WkH, WkL, HH, HH);
    wconv_k<<<dim3(HH / 32, HH / 32, NLAY), 256, 0, stream>>>(Wv, WvH, WvL, HH, HH);
    wconv_k<<<dim3(HH / 32, HH / 32, NLAY), 256, 0, stream>>>(Wo, WoH, WoL, HH, HH);
    wconv_k<<<dim3(FFD / 32, HH / 32, NLAY), 256, 0, stream>>>(Wi, WiH, WiL, HH, FFD);
    wconv_k<<<dim3(HH / 32, FFD / 32, NLAY), 256, 0, stream>>>(Wo2, W2H, W2L, FFD, HH);

    embed_ln_k<<<TOK, 256, 0, stream>>>(ids, tt, wemb, pemb, temb, elg, elb, h, hPH, hPL);

    dim3 gQKV(18, TOK / 64);   // 3 mats x 6 col-blocks
    dim3 gH(HH / 128, TOK / 64);
    dim3 gF(FFD / 128, TOK / 64);

    for (int l = 0; l < NLAY; l++) {
        const size_t w2 = (size_t)l * HH * HH;
        const size_t wf = (size_t)l * HH * FFD;
        const float* bql = bq + (size_t)l * HH;
        const float* bkl = bk + (size_t)l * HH;
        const float* bvl = bv + (size_t)l * HH;
        const float* bol = bo + (size_t)l * HH;
        const float* g1l = g1 + (size_t)l * HH;  const float* b1l = b1 + (size_t)l * HH;
        const float* bil = bi + (size_t)l * FFD;
        const float* b2l_ = bo2 + (size_t)l * HH;
        const float* g2l = g2 + (size_t)l * HH;  const float* b2l = b2 + (size_t)l * HH;

        qkv_k<<<gQKV, 256, 0, stream>>>(hPH, hPL,
            WqH + w2, WqL + w2, WkH + w2, WkL + w2, WvH + w2, WvL + w2,
            bql, bkl, bvl, qb, kb, vb);
        attn_scores_k<<<NB * NHD, 256, 0, stream>>>(qb, kb, mask, sc);
        softmax_k<<<NB * NHD * SS, 64, 0, stream>>>(sc);
        attn_ctx_k<<<NB * NHD, 256, 0, stream>>>(sc, vb, oPH, oPL);
        gemm_k<0><<<gH, 256, 0, stream>>>(oPH, oPL, WoH + w2, WoL + w2,
            bol, qb, nullptr, nullptr, HH, HH);
        resln_k<<<TOK, 256, 0, stream>>>(h, qb, g1l, b1l, hPH, hPL);
        gemm_k<1><<<gF, 256, 0, stream>>>(hPH, hPL, WiH + wf, WiL + wf,
            bil, nullptr, fPH, fPL, FFD, HH);
        gemm_k<0><<<gH, 256, 0, stream>>>(fPH, fPL, W2H + wf, W2L + wf,
            b2l_, qb, nullptr, nullptr, HH, FFD);
        resln_k<<<TOK, 256, 0, stream>>>(h, qb, g2l, b2l, hPH, hPL);
    }

    emissions_k<<<TOK, 64, 0, stream>>>(h, fcw, fcb, emis);
    crf_k<<<NB, 64, 0, stream>>>(emis, tags, mask, cst, cen, ctr, llh);
    loss_k<<<1, 64, 0, stream>>>(llh, loss);
}